// Round 1
// baseline (1940.291 us; speedup 1.0000x reference)
//
#include <hip/hip_runtime.h>
#include <hip/hip_bf16.h>

#define L_SEQ 2048
#define BATCH 2
#define DMODEL 512
#define DINNER 1024
#define DSTATE 16
#define DTRANK 32
#define NP 64  // DT_RANK + 2*D_STATE

__device__ __forceinline__ float sigmoidf_(float x) { return 1.f / (1.f + __expf(-x)); }

// C[M,N] = (A (+A2))[M,K] (lda) @ W[N,K]^T (ldw), fp32, 64x64 tile, 256 thr, 4x4/thr.
// epi 0: C0[r*ldc+c] = v
// epi 1: split at nsplit: C0[r*nsplit+c] (c<nsplit) else C1[r*nsplit+c-nsplit]
// epi 2: C0 = sigmoid(v + bias[c]) * mulsrc[r*ldc+c]
__global__ __launch_bounds__(256) void gemm64(
    const float* __restrict__ A, const float* __restrict__ A2, int lda,
    const float* __restrict__ W, int ldw, int K,
    float* __restrict__ C0, float* __restrict__ C1, int ldc,
    const float* __restrict__ bias, const float* __restrict__ mulsrc,
    int epi, int nsplit)
{
    __shared__ float As[16][65];
    __shared__ float Ws[16][65];
    const int tid = threadIdx.x;
    const int tx = tid & 15, ty = tid >> 4;
    const int row0 = blockIdx.y * 64;
    const int col0 = blockIdx.x * 64;
    const int lr = tid >> 2;         // 0..63
    const int lk = (tid & 3) * 4;    // 0,4,8,12
    float acc[4][4] = {};

    for (int k0 = 0; k0 < K; k0 += 16) {
        float4 av = *(const float4*)(A + (size_t)(row0 + lr) * lda + k0 + lk);
        if (A2) {
            float4 bv = *(const float4*)(A2 + (size_t)(row0 + lr) * lda + k0 + lk);
            av.x += bv.x; av.y += bv.y; av.z += bv.z; av.w += bv.w;
        }
        As[lk + 0][lr] = av.x; As[lk + 1][lr] = av.y;
        As[lk + 2][lr] = av.z; As[lk + 3][lr] = av.w;
        float4 wv = *(const float4*)(W + (size_t)(col0 + lr) * ldw + k0 + lk);
        Ws[lk + 0][lr] = wv.x; Ws[lk + 1][lr] = wv.y;
        Ws[lk + 2][lr] = wv.z; Ws[lk + 3][lr] = wv.w;
        __syncthreads();
        #pragma unroll
        for (int kk = 0; kk < 16; ++kk) {
            float a[4], b[4];
            #pragma unroll
            for (int i = 0; i < 4; ++i) a[i] = As[kk][ty * 4 + i];
            #pragma unroll
            for (int j = 0; j < 4; ++j) b[j] = Ws[kk][tx * 4 + j];
            #pragma unroll
            for (int i = 0; i < 4; ++i)
                #pragma unroll
                for (int j = 0; j < 4; ++j)
                    acc[i][j] = fmaf(a[i], b[j], acc[i][j]);
        }
        __syncthreads();
    }

    #pragma unroll
    for (int i = 0; i < 4; ++i) {
        int r = row0 + ty * 4 + i;
        #pragma unroll
        for (int j = 0; j < 4; ++j) {
            int c = col0 + tx * 4 + j;
            float v = acc[i][j];
            if (epi == 0) {
                C0[(size_t)r * ldc + c] = v;
            } else if (epi == 1) {
                if (c < nsplit) C0[(size_t)r * nsplit + c] = v;
                else            C1[(size_t)r * nsplit + (c - nsplit)] = v;
            } else {
                float g = sigmoidf_(v + bias[c]);
                C0[(size_t)r * ldc + c] = g * mulsrc[(size_t)r * ldc + c];
            }
        }
    }
}

// Depthwise causal conv (h2t) + anti-causal reversed conv (t2h) + SiLU, both dirs.
__global__ __launch_bounds__(256) void conv_silu_kernel(
    const float* __restrict__ xg,
    const float* __restrict__ w0, const float* __restrict__ b0,
    const float* __restrict__ w1, const float* __restrict__ b1,
    float* __restrict__ out0, float* __restrict__ out1)
{
    const int l = blockIdx.x;
    const int b = blockIdx.y;
    const int d0 = threadIdx.x * 4;
    const size_t bbase = (size_t)b * L_SEQ * DINNER + d0;

    float tap[7][4];
    #pragma unroll
    for (int p = 0; p < 7; ++p) {
        int ll = l + p - 3;
        if (ll >= 0 && ll < L_SEQ) {
            float4 v = *(const float4*)(xg + bbase + (size_t)ll * DINNER);
            tap[p][0] = v.x; tap[p][1] = v.y; tap[p][2] = v.z; tap[p][3] = v.w;
        } else {
            tap[p][0] = tap[p][1] = tap[p][2] = tap[p][3] = 0.f;
        }
    }
    float4 bb0 = *(const float4*)(b0 + d0);
    float4 bb1 = *(const float4*)(b1 + d0);
    float r0[4], r1[4];
    #pragma unroll
    for (int i = 0; i < 4; ++i) {
        float4 ww0 = *(const float4*)(w0 + (d0 + i) * 4);
        float4 ww1 = *(const float4*)(w1 + (d0 + i) * 4);
        float a0 = ((const float*)&bb0)[i];
        a0 += ww0.x * tap[0][i] + ww0.y * tap[1][i] + ww0.z * tap[2][i] + ww0.w * tap[3][i];
        float a1 = ((const float*)&bb1)[i];
        // t2h in original coords: tap at l+k gets weight w[3-k]
        a1 += ww1.w * tap[3][i] + ww1.z * tap[4][i] + ww1.y * tap[5][i] + ww1.x * tap[6][i];
        r0[i] = a0 * sigmoidf_(a0);
        r1[i] = a1 * sigmoidf_(a1);
    }
    *(float4*)(out0 + bbase + (size_t)l * DINNER) = make_float4(r0[0], r0[1], r0[2], r0[3]);
    *(float4*)(out1 + bbase + (size_t)l * DINNER) = make_float4(r1[0], r1[1], r1[2], r1[3]);
}

// Selective scan. 16 lanes per (b,d) channel, lane = state n. blockIdx.y = direction.
__global__ __launch_bounds__(256) void scan_kernel(
    const float* __restrict__ delta0, const float* __restrict__ delta1,
    const float* __restrict__ xact0,  const float* __restrict__ xact1,
    const float* __restrict__ ssmp0,  const float* __restrict__ ssmp1,
    const float* __restrict__ camz,
    const float* __restrict__ Alog0,  const float* __restrict__ Alog1,
    const float* __restrict__ Dv0,    const float* __restrict__ Dv1,
    const float* __restrict__ dtb0,   const float* __restrict__ dtb1,
    float* __restrict__ y0, float* __restrict__ y1)
{
    const int dir = blockIdx.y;
    const int tid = threadIdx.x;
    const int n = tid & 15;
    const int g = tid >> 4;
    const int ch = blockIdx.x * 16 + g;     // 0..2047
    const int b = ch >> 10;
    const int d = ch & 1023;

    const float* __restrict__ delta = dir ? delta1 : delta0;
    const float* __restrict__ xact  = dir ? xact1  : xact0;
    const float* __restrict__ ssmp  = dir ? ssmp1  : ssmp0;
    const float* __restrict__ Alog  = dir ? Alog1  : Alog0;
    const float* __restrict__ Dv    = dir ? Dv1    : Dv0;
    const float* __restrict__ dtb   = dir ? dtb1   : dtb0;
    float* __restrict__ yo          = dir ? y1     : y0;

    const float Adn = -__expf(Alog[d * DSTATE + n]);
    const float Dd  = Dv[d];
    const float dtbd = dtb[d];

    const int step = dir ? -1 : 1;
    int l = dir ? (L_SEQ - 1) : 0;
    int idx  = (b * L_SEQ + l) * DINNER + d;
    int pidx = (b * L_SEQ + l) * NP;
    const int idxstep = step * DINNER;
    const int pstep   = step * NP;

    float dv = delta[idx], uv = xact[idx], zv = camz[idx];
    float Bv = ssmp[pidx + DTRANK + n];
    float Cv = ssmp[pidx + DTRANK + DSTATE + n];
    float h = 0.f;

    for (int s = 0; s < L_SEQ; ++s) {
        float dv_n = 0.f, uv_n = 0.f, zv_n = 0.f, Bv_n = 0.f, Cv_n = 0.f;
        if (s + 1 < L_SEQ) {
            int idx2 = idx + idxstep, pidx2 = pidx + pstep;
            dv_n = delta[idx2]; uv_n = xact[idx2]; zv_n = camz[idx2];
            Bv_n = ssmp[pidx2 + DTRANK + n];
            Cv_n = ssmp[pidx2 + DTRANK + DSTATE + n];
        }
        float xsp = dv + dtbd;
        float sp = (xsp > 20.f) ? xsp : log1pf(__expf(xsp));
        float dA = __expf(sp * Adn);
        h = fmaf(dA, h, sp * Bv * uv);
        float part = h * Cv;
        part += __shfl_xor(part, 1);
        part += __shfl_xor(part, 2);
        part += __shfl_xor(part, 4);
        part += __shfl_xor(part, 8);
        if (n == 0) {
            float sz = zv * sigmoidf_(zv);
            yo[idx] = (part + uv * Dd) * sz;
        }
        idx += idxstep; pidx += pstep;
        dv = dv_n; uv = uv_n; zv = zv_n; Bv = Bv_n; Cv = Cv_n;
    }
}

extern "C" void kernel_launch(void* const* d_in, const int* in_sizes, int n_in,
                              void* d_out, int out_size, void* d_ws, size_t ws_size,
                              hipStream_t stream)
{
    const float* lidar_feats  = (const float*)d_in[0];
    const float* camera_feats = (const float*)d_in[1];
    const float* in_proj_w    = (const float*)d_in[2];
    const float* conv_w_h2t   = (const float*)d_in[3];
    const float* conv_b_h2t   = (const float*)d_in[4];
    const float* x_proj_w_h2t = (const float*)d_in[5];
    const float* dt_proj_w_h2t= (const float*)d_in[6];
    const float* dt_proj_b_h2t= (const float*)d_in[7];
    const float* A_log_h2t    = (const float*)d_in[8];
    const float* D_h2t        = (const float*)d_in[9];
    const float* conv_w_t2h   = (const float*)d_in[10];
    const float* conv_b_t2h   = (const float*)d_in[11];
    const float* x_proj_w_t2h = (const float*)d_in[12];
    const float* dt_proj_w_t2h= (const float*)d_in[13];
    const float* dt_proj_b_t2h= (const float*)d_in[14];
    const float* A_log_t2h    = (const float*)d_in[15];
    const float* D_t2h        = (const float*)d_in[16];
    const float* lidar_w      = (const float*)d_in[17];
    const float* lidar_b      = (const float*)d_in[18];
    const float* out_proj_w   = (const float*)d_in[19];
    float* out = (float*)d_out;

    const size_t MN = (size_t)BATCH * L_SEQ * DINNER;  // 4M floats
    float* ws = (float*)d_ws;
    float* cam_x   = ws + 0 * MN;
    float* cam_z   = ws + 1 * MN;
    float* cam_xg  = ws + 2 * MN;
    float* lidar_x = ws + 3 * MN;
    float* xact0   = ws + 4 * MN;
    float* xact1   = ws + 5 * MN;
    float* delta0  = ws + 6 * MN;
    float* delta1  = ws + 7 * MN;
    float* ssmp0   = ws + 8 * MN;                       // 4096*64
    float* ssmp1   = ssmp0 + (size_t)BATCH * L_SEQ * NP;
    float* y0 = lidar_x;  // dead after gate GEMM (stream-ordered reuse)
    float* y1 = cam_xg;   // dead after conv kernel (stream-ordered reuse)

    const int M = BATCH * L_SEQ;  // 4096
    dim3 blk(256);

    // 1. cam_xz = camera @ in_proj^T, split into cam_x / cam_z
    gemm64<<<dim3(2048 / 64, M / 64), blk, 0, stream>>>(
        camera_feats, nullptr, DMODEL, in_proj_w, DMODEL, DMODEL,
        cam_x, cam_z, 0, nullptr, nullptr, 1, DINNER);
    // 2. lidar_x = lidar @ in_proj[:DINNER]^T
    gemm64<<<dim3(DINNER / 64, M / 64), blk, 0, stream>>>(
        lidar_feats, nullptr, DMODEL, in_proj_w, DMODEL, DMODEL,
        lidar_x, nullptr, DINNER, nullptr, nullptr, 0, 0);
    // 3. cam_xg = sigmoid(lidar_x @ lidar_w^T + lidar_b) * cam_x
    gemm64<<<dim3(DINNER / 64, M / 64), blk, 0, stream>>>(
        lidar_x, nullptr, DINNER, lidar_w, DINNER, DINNER,
        cam_xg, nullptr, DINNER, lidar_b, cam_x, 2, 0);
    // 4/5. ssm_p (dt_r | B | C) per direction
    gemm64<<<dim3(1, M / 64), blk, 0, stream>>>(
        cam_x, nullptr, DINNER, x_proj_w_h2t, DINNER, DINNER,
        ssmp0, nullptr, NP, nullptr, nullptr, 0, 0);
    gemm64<<<dim3(1, M / 64), blk, 0, stream>>>(
        cam_x, nullptr, DINNER, x_proj_w_t2h, DINNER, DINNER,
        ssmp1, nullptr, NP, nullptr, nullptr, 0, 0);
    // 6/7. delta = dt_r @ dt_proj^T (softplus+bias folded into scan)
    gemm64<<<dim3(DINNER / 64, M / 64), blk, 0, stream>>>(
        ssmp0, nullptr, NP, dt_proj_w_h2t, DTRANK, DTRANK,
        delta0, nullptr, DINNER, nullptr, nullptr, 0, 0);
    gemm64<<<dim3(DINNER / 64, M / 64), blk, 0, stream>>>(
        ssmp1, nullptr, NP, dt_proj_w_t2h, DTRANK, DTRANK,
        delta1, nullptr, DINNER, nullptr, nullptr, 0, 0);
    // 8. conv + SiLU, both directions
    conv_silu_kernel<<<dim3(L_SEQ, BATCH), blk, 0, stream>>>(
        cam_xg, conv_w_h2t, conv_b_h2t, conv_w_t2h, conv_b_t2h, xact0, xact1);
    // 9. selective scan, both directions
    scan_kernel<<<dim3(BATCH * DINNER / 16, 2), blk, 0, stream>>>(
        delta0, delta1, xact0, xact1, ssmp0, ssmp1, cam_z,
        A_log_h2t, A_log_t2h, D_h2t, D_t2h, dt_proj_b_h2t, dt_proj_b_t2h, y0, y1);
    // 10. out = (y0 + y1) @ out_proj^T
    gemm64<<<dim3(DMODEL / 64, M / 64), blk, 0, stream>>>(
        y0, y1, DINNER, out_proj_w, DINNER, DINNER,
        out, nullptr, DMODEL, nullptr, nullptr, 0, 0);
}

// Round 2
// 990.717 us; speedup vs baseline: 1.9585x; 1.9585x over previous
//
#include <hip/hip_runtime.h>
#include <hip/hip_bf16.h>

#define L_SEQ 2048
#define BATCH 2
#define DMODEL 512
#define DINNER 1024
#define DSTATE 16
#define DTRANK 32
#define NP 64   // DT_RANK + 2*D_STATE
#define CH 32   // scan chunks
#define LC 64   // L_SEQ / CH

__device__ __forceinline__ float sigmoidf_(float x) { return 1.f / (1.f + __expf(-x)); }

// C[M,N] = (A (+A2))[M,K] (lda) @ W[N,K]^T (ldw), fp32, 64x64 tile, 256 thr, 4x4/thr.
// epi 0: C0[r*ldc+c] = v
// epi 1: split at nsplit: C0[r*nsplit+c] (c<nsplit) else C1[r*nsplit+c-nsplit]
// epi 2: C0 = sigmoid(v + bias[c]) * mulsrc[r*ldc+c]
// epi 3: C0 = softplus(v + bias[c])
__global__ __launch_bounds__(256) void gemm64(
    const float* __restrict__ A, const float* __restrict__ A2, int lda,
    const float* __restrict__ W, int ldw, int K,
    float* __restrict__ C0, float* __restrict__ C1, int ldc,
    const float* __restrict__ bias, const float* __restrict__ mulsrc,
    int epi, int nsplit)
{
    __shared__ float As[16][65];
    __shared__ float Ws[16][65];
    const int tid = threadIdx.x;
    const int tx = tid & 15, ty = tid >> 4;
    const int row0 = blockIdx.y * 64;
    const int col0 = blockIdx.x * 64;
    const int lr = tid >> 2;         // 0..63
    const int lk = (tid & 3) * 4;    // 0,4,8,12
    float acc[4][4] = {};

    for (int k0 = 0; k0 < K; k0 += 16) {
        float4 av = *(const float4*)(A + (size_t)(row0 + lr) * lda + k0 + lk);
        if (A2) {
            float4 bv = *(const float4*)(A2 + (size_t)(row0 + lr) * lda + k0 + lk);
            av.x += bv.x; av.y += bv.y; av.z += bv.z; av.w += bv.w;
        }
        As[lk + 0][lr] = av.x; As[lk + 1][lr] = av.y;
        As[lk + 2][lr] = av.z; As[lk + 3][lr] = av.w;
        float4 wv = *(const float4*)(W + (size_t)(col0 + lr) * ldw + k0 + lk);
        Ws[lk + 0][lr] = wv.x; Ws[lk + 1][lr] = wv.y;
        Ws[lk + 2][lr] = wv.z; Ws[lk + 3][lr] = wv.w;
        __syncthreads();
        #pragma unroll
        for (int kk = 0; kk < 16; ++kk) {
            float a[4], b[4];
            #pragma unroll
            for (int i = 0; i < 4; ++i) a[i] = As[kk][ty * 4 + i];
            #pragma unroll
            for (int j = 0; j < 4; ++j) b[j] = Ws[kk][tx * 4 + j];
            #pragma unroll
            for (int i = 0; i < 4; ++i)
                #pragma unroll
                for (int j = 0; j < 4; ++j)
                    acc[i][j] = fmaf(a[i], b[j], acc[i][j]);
        }
        __syncthreads();
    }

    #pragma unroll
    for (int i = 0; i < 4; ++i) {
        int r = row0 + ty * 4 + i;
        #pragma unroll
        for (int j = 0; j < 4; ++j) {
            int c = col0 + tx * 4 + j;
            float v = acc[i][j];
            if (epi == 0) {
                C0[(size_t)r * ldc + c] = v;
            } else if (epi == 1) {
                if (c < nsplit) C0[(size_t)r * nsplit + c] = v;
                else            C1[(size_t)r * nsplit + (c - nsplit)] = v;
            } else if (epi == 2) {
                float g = sigmoidf_(v + bias[c]);
                C0[(size_t)r * ldc + c] = g * mulsrc[(size_t)r * ldc + c];
            } else {
                float x = v + bias[c];
                float sp = (x > 20.f) ? x : __logf(1.f + __expf(x));
                C0[(size_t)r * ldc + c] = sp;
            }
        }
    }
}

// Depthwise causal conv (h2t) + anti-causal reversed conv (t2h) + SiLU, both dirs.
__global__ __launch_bounds__(256) void conv_silu_kernel(
    const float* __restrict__ xg,
    const float* __restrict__ w0, const float* __restrict__ b0,
    const float* __restrict__ w1, const float* __restrict__ b1,
    float* __restrict__ out0, float* __restrict__ out1)
{
    const int l = blockIdx.x;
    const int b = blockIdx.y;
    const int d0 = threadIdx.x * 4;
    const size_t bbase = (size_t)b * L_SEQ * DINNER + d0;

    float tap[7][4];
    #pragma unroll
    for (int p = 0; p < 7; ++p) {
        int ll = l + p - 3;
        if (ll >= 0 && ll < L_SEQ) {
            float4 v = *(const float4*)(xg + bbase + (size_t)ll * DINNER);
            tap[p][0] = v.x; tap[p][1] = v.y; tap[p][2] = v.z; tap[p][3] = v.w;
        } else {
            tap[p][0] = tap[p][1] = tap[p][2] = tap[p][3] = 0.f;
        }
    }
    float4 bb0 = *(const float4*)(b0 + d0);
    float4 bb1 = *(const float4*)(b1 + d0);
    float r0[4], r1[4];
    #pragma unroll
    for (int i = 0; i < 4; ++i) {
        float4 ww0 = *(const float4*)(w0 + (d0 + i) * 4);
        float4 ww1 = *(const float4*)(w1 + (d0 + i) * 4);
        float a0 = ((const float*)&bb0)[i];
        a0 += ww0.x * tap[0][i] + ww0.y * tap[1][i] + ww0.z * tap[2][i] + ww0.w * tap[3][i];
        float a1 = ((const float*)&bb1)[i];
        a1 += ww1.w * tap[3][i] + ww1.z * tap[4][i] + ww1.y * tap[5][i] + ww1.x * tap[6][i];
        r0[i] = a0 * sigmoidf_(a0);
        r1[i] = a1 * sigmoidf_(a1);
    }
    *(float4*)(out0 + bbase + (size_t)l * DINNER) = make_float4(r0[0], r0[1], r0[2], r0[3]);
    *(float4*)(out1 + bbase + (size_t)l * DINNER) = make_float4(r1[0], r1[1], r1[2], r1[3]);
}

// ---- Chunked selective scan ----
// Group = 16 lanes = one (dir,b,d,chunk); lane = state n.
// gid = ((dir*BATCH + b)*CH + chunk)*DINNER + d   (d fastest for coalesced PA/hC writes)

__global__ __launch_bounds__(256) void scan_phase1(
    const float* __restrict__ sp0, const float* __restrict__ sp1,
    const float* __restrict__ xact0, const float* __restrict__ xact1,
    const float* __restrict__ ssmp0, const float* __restrict__ ssmp1,
    const float* __restrict__ Alog0, const float* __restrict__ Alog1,
    float* __restrict__ PA, float* __restrict__ hC)
{
    const int flat = blockIdx.x * 256 + threadIdx.x;
    const int n = flat & 15;
    const int gid = flat >> 4;
    const int d = gid & (DINNER - 1);
    const int rest = gid >> 10;          // (dir*2+b)*CH + chunk
    const int chunk = rest & (CH - 1);
    const int bb = rest >> 5;
    const int b = bb & 1;
    const int dir = bb >> 1;

    const float* __restrict__ sp = dir ? sp1 : sp0;
    const float* __restrict__ u  = dir ? xact1 : xact0;
    const float* __restrict__ Bm = dir ? ssmp1 : ssmp0;
    const float* __restrict__ Alog = dir ? Alog1 : Alog0;

    const float Adn = -__expf(Alog[d * DSTATE + n]);
    const int step = dir ? -1 : 1;
    const int l0 = dir ? (L_SEQ - 1 - chunk * LC) : (chunk * LC);
    int idx  = (b * L_SEQ + l0) * DINNER + d;
    int pidx = (b * L_SEQ + l0) * NP + DTRANK + n;
    const int idxstep = step * DINNER, pstep = step * NP;

    float pa = 1.f, h = 0.f;
    #pragma unroll 4
    for (int s = 0; s < LC; ++s) {
        float spv = sp[idx];
        float uv  = u[idx];
        float Bv  = Bm[pidx];
        float dA  = __expf(spv * Adn);
        pa *= dA;
        h = fmaf(dA, h, spv * Bv * uv);
        idx += idxstep; pidx += pstep;
    }
    const int o = rest * (DINNER * DSTATE) + d * DSTATE + n;
    PA[o] = pa;
    hC[o] = h;
}

// Exclusive scan over chunk carries; writes carry-in over PA in place.
__global__ __launch_bounds__(256) void scan_phase2(
    float* __restrict__ PA, const float* __restrict__ hC)
{
    const int flat = blockIdx.x * 256 + threadIdx.x;   // ((dir*2+b)*DINNER + d)*16 + n
    const int dn = flat & (DINNER * DSTATE - 1);
    const int bb = flat >> 14;
    const int base = bb * CH * (DINNER * DSTATE) + dn;
    float hrun = 0.f;
    #pragma unroll 4
    for (int c = 0; c < CH; ++c) {
        const int o = base + c * (DINNER * DSTATE);
        float pa = PA[o];
        float hc = hC[o];
        PA[o] = hrun;
        hrun = fmaf(pa, hrun, hc);
    }
}

__global__ __launch_bounds__(256) void scan_phase3(
    const float* __restrict__ sp0, const float* __restrict__ sp1,
    const float* __restrict__ xact0, const float* __restrict__ xact1,
    const float* __restrict__ ssmp0, const float* __restrict__ ssmp1,
    const float* __restrict__ camz,
    const float* __restrict__ Alog0, const float* __restrict__ Alog1,
    const float* __restrict__ Dv0, const float* __restrict__ Dv1,
    const float* __restrict__ hin,
    float* __restrict__ y0, float* __restrict__ y1)
{
    const int flat = blockIdx.x * 256 + threadIdx.x;
    const int n = flat & 15;
    const int gid = flat >> 4;
    const int d = gid & (DINNER - 1);
    const int rest = gid >> 10;
    const int chunk = rest & (CH - 1);
    const int bb = rest >> 5;
    const int b = bb & 1;
    const int dir = bb >> 1;

    const float* __restrict__ sp = dir ? sp1 : sp0;
    const float* __restrict__ u  = dir ? xact1 : xact0;
    const float* __restrict__ Pm = dir ? ssmp1 : ssmp0;
    const float* __restrict__ Alog = dir ? Alog1 : Alog0;
    const float* __restrict__ Dv = dir ? Dv1 : Dv0;
    float* __restrict__ yo = dir ? y1 : y0;

    const float Adn = -__expf(Alog[d * DSTATE + n]);
    const float Dd = Dv[d];
    const int step = dir ? -1 : 1;
    const int l0 = dir ? (L_SEQ - 1 - chunk * LC) : (chunk * LC);
    int idx  = (b * L_SEQ + l0) * DINNER + d;
    int pidx = (b * L_SEQ + l0) * NP + DTRANK + n;
    const int idxstep = step * DINNER, pstep = step * NP;

    float h = hin[rest * (DINNER * DSTATE) + d * DSTATE + n];

    #pragma unroll 2
    for (int s = 0; s < LC; ++s) {
        float spv = sp[idx];
        float uv  = u[idx];
        float zv  = camz[idx];
        float Bv  = Pm[pidx];
        float Cv  = Pm[pidx + DSTATE];
        float dA  = __expf(spv * Adn);
        h = fmaf(dA, h, spv * Bv * uv);
        float part = h * Cv;
        part += __shfl_xor(part, 1);
        part += __shfl_xor(part, 2);
        part += __shfl_xor(part, 4);
        part += __shfl_xor(part, 8);
        if (n == 0) {
            float sz = zv * sigmoidf_(zv);
            yo[idx] = (part + uv * Dd) * sz;
        }
        idx += idxstep; pidx += pstep;
    }
}

extern "C" void kernel_launch(void* const* d_in, const int* in_sizes, int n_in,
                              void* d_out, int out_size, void* d_ws, size_t ws_size,
                              hipStream_t stream)
{
    const float* lidar_feats  = (const float*)d_in[0];
    const float* camera_feats = (const float*)d_in[1];
    const float* in_proj_w    = (const float*)d_in[2];
    const float* conv_w_h2t   = (const float*)d_in[3];
    const float* conv_b_h2t   = (const float*)d_in[4];
    const float* x_proj_w_h2t = (const float*)d_in[5];
    const float* dt_proj_w_h2t= (const float*)d_in[6];
    const float* dt_proj_b_h2t= (const float*)d_in[7];
    const float* A_log_h2t    = (const float*)d_in[8];
    const float* D_h2t        = (const float*)d_in[9];
    const float* conv_w_t2h   = (const float*)d_in[10];
    const float* conv_b_t2h   = (const float*)d_in[11];
    const float* x_proj_w_t2h = (const float*)d_in[12];
    const float* dt_proj_w_t2h= (const float*)d_in[13];
    const float* dt_proj_b_t2h= (const float*)d_in[14];
    const float* A_log_t2h    = (const float*)d_in[15];
    const float* D_t2h        = (const float*)d_in[16];
    const float* lidar_w      = (const float*)d_in[17];
    const float* lidar_b      = (const float*)d_in[18];
    const float* out_proj_w   = (const float*)d_in[19];
    float* out = (float*)d_out;

    const size_t MN = (size_t)BATCH * L_SEQ * DINNER;   // 4M floats
    const size_t PS = (size_t)BATCH * L_SEQ * NP;       // 256K floats
    float* ws = (float*)d_ws;
    float* cam_x   = ws + 0 * MN;
    float* cam_z   = ws + 1 * MN;
    float* cam_xg  = ws + 2 * MN;
    float* lidar_x = ws + 3 * MN;
    float* xact0   = ws + 4 * MN;
    float* xact1   = ws + 5 * MN;
    float* sp0     = ws + 6 * MN;   // softplus(delta+bias), precomputed in GEMM epi
    float* sp1     = ws + 7 * MN;
    float* ssmp0   = ws + 8 * MN;
    float* ssmp1   = ssmp0 + PS;
    float* hC      = ssmp1 + PS;    // 4M floats
    float* PA      = cam_x;         // dead after x_proj/gate GEMMs; exactly MN floats
    float* y0 = lidar_x;            // dead after gate GEMM
    float* y1 = cam_xg;             // dead after conv kernel

    const int M = BATCH * L_SEQ;    // 4096
    dim3 blk(256);

    // 1. cam_xz = camera @ in_proj^T, split into cam_x / cam_z
    gemm64<<<dim3(2048 / 64, M / 64), blk, 0, stream>>>(
        camera_feats, nullptr, DMODEL, in_proj_w, DMODEL, DMODEL,
        cam_x, cam_z, 0, nullptr, nullptr, 1, DINNER);
    // 2. lidar_x = lidar @ in_proj[:DINNER]^T
    gemm64<<<dim3(DINNER / 64, M / 64), blk, 0, stream>>>(
        lidar_feats, nullptr, DMODEL, in_proj_w, DMODEL, DMODEL,
        lidar_x, nullptr, DINNER, nullptr, nullptr, 0, 0);
    // 3. cam_xg = sigmoid(lidar_x @ lidar_w^T + lidar_b) * cam_x
    gemm64<<<dim3(DINNER / 64, M / 64), blk, 0, stream>>>(
        lidar_x, nullptr, DINNER, lidar_w, DINNER, DINNER,
        cam_xg, nullptr, DINNER, lidar_b, cam_x, 2, 0);
    // 4/5. ssm_p (dt_r | B | C) per direction
    gemm64<<<dim3(1, M / 64), blk, 0, stream>>>(
        cam_x, nullptr, DINNER, x_proj_w_h2t, DINNER, DINNER,
        ssmp0, nullptr, NP, nullptr, nullptr, 0, 0);
    gemm64<<<dim3(1, M / 64), blk, 0, stream>>>(
        cam_x, nullptr, DINNER, x_proj_w_t2h, DINNER, DINNER,
        ssmp1, nullptr, NP, nullptr, nullptr, 0, 0);
    // 6/7. sp = softplus(dt_r @ dt_proj^T + dt_bias)
    gemm64<<<dim3(DINNER / 64, M / 64), blk, 0, stream>>>(
        ssmp0, nullptr, NP, dt_proj_w_h2t, DTRANK, DTRANK,
        sp0, nullptr, DINNER, dt_proj_b_h2t, nullptr, 3, 0);
    gemm64<<<dim3(DINNER / 64, M / 64), blk, 0, stream>>>(
        ssmp1, nullptr, NP, dt_proj_w_t2h, DTRANK, DTRANK,
        sp1, nullptr, DINNER, dt_proj_b_t2h, nullptr, 3, 0);
    // 8. conv + SiLU, both directions
    conv_silu_kernel<<<dim3(L_SEQ, BATCH), blk, 0, stream>>>(
        cam_xg, conv_w_h2t, conv_b_h2t, conv_w_t2h, conv_b_t2h, xact0, xact1);
    // 9. chunked scan
    const int ngroups = 2 * BATCH * CH * DINNER;           // 131072
    scan_phase1<<<dim3(ngroups * 16 / 256), blk, 0, stream>>>(
        sp0, sp1, xact0, xact1, ssmp0, ssmp1, A_log_h2t, A_log_t2h, PA, hC);
    scan_phase2<<<dim3(2 * BATCH * DINNER * DSTATE / 256), blk, 0, stream>>>(PA, hC);
    scan_phase3<<<dim3(ngroups * 16 / 256), blk, 0, stream>>>(
        sp0, sp1, xact0, xact1, ssmp0, ssmp1, cam_z,
        A_log_h2t, A_log_t2h, D_h2t, D_t2h, PA, y0, y1);
    // 10. out = (y0 + y1) @ out_proj^T
    gemm64<<<dim3(DMODEL / 64, M / 64), blk, 0, stream>>>(
        y0, y1, DINNER, out_proj_w, DINNER, DINNER,
        out, nullptr, DMODEL, nullptr, nullptr, 0, 0);
}

// Round 3
// 804.720 us; speedup vs baseline: 2.4111x; 1.2311x over previous
//
#include <hip/hip_runtime.h>
#include <hip/hip_bf16.h>

#define L_SEQ 2048
#define BATCH 2
#define DMODEL 512
#define DINNER 1024
#define DSTATE 16
#define DTRANK 32
#define NP 64   // DT_RANK + 2*D_STATE
#define CH 32   // scan chunks
#define LC 64   // L_SEQ / CH

__device__ __forceinline__ float sigmoidf_(float x) { return 1.f / (1.f + __expf(-x)); }

// C[M,N] = (A (+A2))[M,K] (lda) @ W[N,K]^T (ldw), fp32, 64x64 tile, 256 thr, 4x4/thr.
// epi 0: C0[r*ldc+c] = v
// epi 1: split at nsplit: C0[r*nsplit+c] (c<nsplit) else C1[r*nsplit+c-nsplit]
// epi 2: C0 = sigmoid(v + bias[c]) * mulsrc[r*ldc+c]
// epi 3: C0 = softplus(v + bias[c])
__global__ __launch_bounds__(256) void gemm64(
    const float* __restrict__ A, const float* __restrict__ A2, int lda,
    const float* __restrict__ W, int ldw, int K,
    float* __restrict__ C0, float* __restrict__ C1, int ldc,
    const float* __restrict__ bias, const float* __restrict__ mulsrc,
    int epi, int nsplit)
{
    __shared__ float As[16][65];
    __shared__ float Ws[16][65];
    const int tid = threadIdx.x;
    const int tx = tid & 15, ty = tid >> 4;
    const int row0 = blockIdx.y * 64;
    const int col0 = blockIdx.x * 64;
    const int lr = tid >> 2;         // 0..63
    const int lk = (tid & 3) * 4;    // 0,4,8,12
    float acc[4][4] = {};

    for (int k0 = 0; k0 < K; k0 += 16) {
        float4 av = *(const float4*)(A + (size_t)(row0 + lr) * lda + k0 + lk);
        if (A2) {
            float4 bv = *(const float4*)(A2 + (size_t)(row0 + lr) * lda + k0 + lk);
            av.x += bv.x; av.y += bv.y; av.z += bv.z; av.w += bv.w;
        }
        As[lk + 0][lr] = av.x; As[lk + 1][lr] = av.y;
        As[lk + 2][lr] = av.z; As[lk + 3][lr] = av.w;
        float4 wv = *(const float4*)(W + (size_t)(col0 + lr) * ldw + k0 + lk);
        Ws[lk + 0][lr] = wv.x; Ws[lk + 1][lr] = wv.y;
        Ws[lk + 2][lr] = wv.z; Ws[lk + 3][lr] = wv.w;
        __syncthreads();
        #pragma unroll
        for (int kk = 0; kk < 16; ++kk) {
            float a[4], b[4];
            #pragma unroll
            for (int i = 0; i < 4; ++i) a[i] = As[kk][ty * 4 + i];
            #pragma unroll
            for (int j = 0; j < 4; ++j) b[j] = Ws[kk][tx * 4 + j];
            #pragma unroll
            for (int i = 0; i < 4; ++i)
                #pragma unroll
                for (int j = 0; j < 4; ++j)
                    acc[i][j] = fmaf(a[i], b[j], acc[i][j]);
        }
        __syncthreads();
    }

    #pragma unroll
    for (int i = 0; i < 4; ++i) {
        int r = row0 + ty * 4 + i;
        #pragma unroll
        for (int j = 0; j < 4; ++j) {
            int c = col0 + tx * 4 + j;
            float v = acc[i][j];
            if (epi == 0) {
                C0[(size_t)r * ldc + c] = v;
            } else if (epi == 1) {
                if (c < nsplit) C0[(size_t)r * nsplit + c] = v;
                else            C1[(size_t)r * nsplit + (c - nsplit)] = v;
            } else if (epi == 2) {
                float g = sigmoidf_(v + bias[c]);
                C0[(size_t)r * ldc + c] = g * mulsrc[(size_t)r * ldc + c];
            } else {
                float x = v + bias[c];
                float sp = (x > 20.f) ? x : __logf(1.f + __expf(x));
                C0[(size_t)r * ldc + c] = sp;
            }
        }
    }
}

// Depthwise causal conv (h2t) + anti-causal reversed conv (t2h) + SiLU, both dirs.
__global__ __launch_bounds__(256) void conv_silu_kernel(
    const float* __restrict__ xg,
    const float* __restrict__ w0, const float* __restrict__ b0,
    const float* __restrict__ w1, const float* __restrict__ b1,
    float* __restrict__ out0, float* __restrict__ out1)
{
    const int l = blockIdx.x;
    const int b = blockIdx.y;
    const int d0 = threadIdx.x * 4;
    const size_t bbase = (size_t)b * L_SEQ * DINNER + d0;

    float tap[7][4];
    #pragma unroll
    for (int p = 0; p < 7; ++p) {
        int ll = l + p - 3;
        if (ll >= 0 && ll < L_SEQ) {
            float4 v = *(const float4*)(xg + bbase + (size_t)ll * DINNER);
            tap[p][0] = v.x; tap[p][1] = v.y; tap[p][2] = v.z; tap[p][3] = v.w;
        } else {
            tap[p][0] = tap[p][1] = tap[p][2] = tap[p][3] = 0.f;
        }
    }
    float4 bb0 = *(const float4*)(b0 + d0);
    float4 bb1 = *(const float4*)(b1 + d0);
    float r0[4], r1[4];
    #pragma unroll
    for (int i = 0; i < 4; ++i) {
        float4 ww0 = *(const float4*)(w0 + (d0 + i) * 4);
        float4 ww1 = *(const float4*)(w1 + (d0 + i) * 4);
        float a0 = ((const float*)&bb0)[i];
        a0 += ww0.x * tap[0][i] + ww0.y * tap[1][i] + ww0.z * tap[2][i] + ww0.w * tap[3][i];
        float a1 = ((const float*)&bb1)[i];
        a1 += ww1.w * tap[3][i] + ww1.z * tap[4][i] + ww1.y * tap[5][i] + ww1.x * tap[6][i];
        r0[i] = a0 * sigmoidf_(a0);
        r1[i] = a1 * sigmoidf_(a1);
    }
    *(float4*)(out0 + bbase + (size_t)l * DINNER) = make_float4(r0[0], r0[1], r0[2], r0[3]);
    *(float4*)(out1 + bbase + (size_t)l * DINNER) = make_float4(r1[0], r1[1], r1[2], r1[3]);
}

// ---- Chunked selective scan, lane-owns-half-channel ----
// Thread = (dir,b,chunk,d,half): owns 8 states in registers, iterates the chunk.
// flat = ((((dir*2+b)*CH + chunk)*DINNER) + d)*2 + half
// B/C for the chunk are block-uniform -> staged in LDS once, broadcast reads.

__global__ __launch_bounds__(256) void scan_phase1(
    const float* __restrict__ sp0, const float* __restrict__ sp1,
    const float* __restrict__ xa0, const float* __restrict__ xa1,
    const float* __restrict__ pm0, const float* __restrict__ pm1,
    const float* __restrict__ Alog0, const float* __restrict__ Alog1,
    float* __restrict__ PA, float* __restrict__ hC)
{
    __shared__ float sBC[LC][32];
    const int tid = threadIdx.x;
    const int flat = blockIdx.x * 256 + tid;
    const int half = flat & 1;
    const int d = (flat >> 1) & (DINNER - 1);
    const int rest = flat >> 11;         // (dir*2+b)*CH + chunk
    const int chunk = rest & (CH - 1);
    const int bb = rest >> 5;
    const int b = bb & 1;
    const int dir = bb >> 1;

    const float* __restrict__ sp = dir ? sp1 : sp0;
    const float* __restrict__ u  = dir ? xa1 : xa0;
    const float* __restrict__ pm = dir ? pm1 : pm0;
    const float* __restrict__ Alog = dir ? Alog1 : Alog0;

    const int step = dir ? -1 : 1;
    const int l0 = dir ? (L_SEQ - 1 - chunk * LC) : (chunk * LC);

    {   // stage B|C rows for this chunk (block-uniform)
        const int base = (b * L_SEQ + l0) * NP + DTRANK;
        #pragma unroll
        for (int j = 0; j < (LC * 32) / 256; ++j) {
            int e = tid + j * 256;
            int s = e >> 5, k = e & 31;
            sBC[s][k] = pm[base + step * s * NP + k];
        }
    }
    __syncthreads();

    float Adn[8];
    #pragma unroll
    for (int n = 0; n < 8; ++n)
        Adn[n] = -__expf(Alog[d * DSTATE + half * 8 + n]);

    int idx = (b * L_SEQ + l0) * DINNER + d;
    const int idxstep = step * DINNER;

    float h[8] = {0.f,0.f,0.f,0.f,0.f,0.f,0.f,0.f};
    float pa[8] = {1.f,1.f,1.f,1.f,1.f,1.f,1.f,1.f};

    float spv = sp[idx], uv = u[idx];
    for (int s = 0; s < LC; ++s) {
        const int idx2 = idx + ((s + 1 < LC) ? idxstep : 0);
        float spn = sp[idx2], un = u[idx2];
        float4 Bv0 = *(const float4*)&sBC[s][half * 8];
        float4 Bv1 = *(const float4*)&sBC[s][half * 8 + 4];
        float sbu = spv * uv;
        const float* Bp0 = (const float*)&Bv0;
        const float* Bp1 = (const float*)&Bv1;
        #pragma unroll
        for (int n = 0; n < 8; ++n) {
            float dA = __expf(spv * Adn[n]);
            pa[n] *= dA;
            float Bn = (n < 4) ? Bp0[n] : Bp1[n - 4];
            h[n] = fmaf(dA, h[n], Bn * sbu);
        }
        idx += idxstep; spv = spn; uv = un;
    }

    const int o = rest * (DINNER * DSTATE) + d * DSTATE + half * 8;
    *(float4*)&PA[o]     = make_float4(pa[0], pa[1], pa[2], pa[3]);
    *(float4*)&PA[o + 4] = make_float4(pa[4], pa[5], pa[6], pa[7]);
    *(float4*)&hC[o]     = make_float4(h[0], h[1], h[2], h[3]);
    *(float4*)&hC[o + 4] = make_float4(h[4], h[5], h[6], h[7]);
}

// Exclusive scan over chunk carries; writes carry-in over PA in place. (unchanged)
__global__ __launch_bounds__(256) void scan_phase2(
    float* __restrict__ PA, const float* __restrict__ hC)
{
    const int flat = blockIdx.x * 256 + threadIdx.x;   // ((dir*2+b)*DINNER + d)*16 + n
    const int dn = flat & (DINNER * DSTATE - 1);
    const int bb = flat >> 14;
    const int base = bb * CH * (DINNER * DSTATE) + dn;
    float hrun = 0.f;
    #pragma unroll 4
    for (int c = 0; c < CH; ++c) {
        const int o = base + c * (DINNER * DSTATE);
        float pa = PA[o];
        float hc = hC[o];
        PA[o] = hrun;
        hrun = fmaf(pa, hrun, hc);
    }
}

__global__ __launch_bounds__(256) void scan_phase3(
    const float* __restrict__ sp0, const float* __restrict__ sp1,
    const float* __restrict__ xa0, const float* __restrict__ xa1,
    const float* __restrict__ pm0, const float* __restrict__ pm1,
    const float* __restrict__ camz,
    const float* __restrict__ Alog0, const float* __restrict__ Alog1,
    const float* __restrict__ Dv0, const float* __restrict__ Dv1,
    const float* __restrict__ hin,
    float* __restrict__ y0, float* __restrict__ y1)
{
    __shared__ float sBC[LC][32];
    const int tid = threadIdx.x;
    const int flat = blockIdx.x * 256 + tid;
    const int half = flat & 1;
    const int d = (flat >> 1) & (DINNER - 1);
    const int rest = flat >> 11;
    const int chunk = rest & (CH - 1);
    const int bb = rest >> 5;
    const int b = bb & 1;
    const int dir = bb >> 1;

    const float* __restrict__ sp = dir ? sp1 : sp0;
    const float* __restrict__ u  = dir ? xa1 : xa0;
    const float* __restrict__ pm = dir ? pm1 : pm0;
    const float* __restrict__ Alog = dir ? Alog1 : Alog0;
    const float* __restrict__ Dv = dir ? Dv1 : Dv0;
    float* __restrict__ yo = dir ? y1 : y0;

    const int step = dir ? -1 : 1;
    const int l0 = dir ? (L_SEQ - 1 - chunk * LC) : (chunk * LC);

    {   // stage B|C rows for this chunk (block-uniform)
        const int base = (b * L_SEQ + l0) * NP + DTRANK;
        #pragma unroll
        for (int j = 0; j < (LC * 32) / 256; ++j) {
            int e = tid + j * 256;
            int s = e >> 5, k = e & 31;
            sBC[s][k] = pm[base + step * s * NP + k];
        }
    }
    __syncthreads();

    float Adn[8];
    #pragma unroll
    for (int n = 0; n < 8; ++n)
        Adn[n] = -__expf(Alog[d * DSTATE + half * 8 + n]);
    const float Dd = Dv[d];

    int idx = (b * L_SEQ + l0) * DINNER + d;
    const int idxstep = step * DINNER;

    const int o = rest * (DINNER * DSTATE) + d * DSTATE + half * 8;
    float4 h0 = *(const float4*)&hin[o];
    float4 h1 = *(const float4*)&hin[o + 4];
    float h[8] = {h0.x, h0.y, h0.z, h0.w, h1.x, h1.y, h1.z, h1.w};

    float spv = sp[idx], uv = u[idx], zv = camz[idx];
    for (int s = 0; s < LC; ++s) {
        const int idx2 = idx + ((s + 1 < LC) ? idxstep : 0);
        float spn = sp[idx2], un = u[idx2], zn = camz[idx2];
        float4 Bv0 = *(const float4*)&sBC[s][half * 8];
        float4 Bv1 = *(const float4*)&sBC[s][half * 8 + 4];
        float4 Cv0 = *(const float4*)&sBC[s][16 + half * 8];
        float4 Cv1 = *(const float4*)&sBC[s][16 + half * 8 + 4];
        const float* Bp0 = (const float*)&Bv0;
        const float* Bp1 = (const float*)&Bv1;
        const float* Cp0 = (const float*)&Cv0;
        const float* Cp1 = (const float*)&Cv1;
        float sbu = spv * uv;
        float acc = 0.f;
        #pragma unroll
        for (int n = 0; n < 8; ++n) {
            float dA = __expf(spv * Adn[n]);
            float Bn = (n < 4) ? Bp0[n] : Bp1[n - 4];
            float Cn = (n < 4) ? Cp0[n] : Cp1[n - 4];
            h[n] = fmaf(dA, h[n], Bn * sbu);
            acc = fmaf(h[n], Cn, acc);
        }
        acc += __shfl_xor(acc, 1);
        if (half == 0) {
            float sz = zv * sigmoidf_(zv);
            yo[idx] = (acc + uv * Dd) * sz;
        }
        idx += idxstep; spv = spn; uv = un; zv = zn;
    }
}

extern "C" void kernel_launch(void* const* d_in, const int* in_sizes, int n_in,
                              void* d_out, int out_size, void* d_ws, size_t ws_size,
                              hipStream_t stream)
{
    const float* lidar_feats  = (const float*)d_in[0];
    const float* camera_feats = (const float*)d_in[1];
    const float* in_proj_w    = (const float*)d_in[2];
    const float* conv_w_h2t   = (const float*)d_in[3];
    const float* conv_b_h2t   = (const float*)d_in[4];
    const float* x_proj_w_h2t = (const float*)d_in[5];
    const float* dt_proj_w_h2t= (const float*)d_in[6];
    const float* dt_proj_b_h2t= (const float*)d_in[7];
    const float* A_log_h2t    = (const float*)d_in[8];
    const float* D_h2t        = (const float*)d_in[9];
    const float* conv_w_t2h   = (const float*)d_in[10];
    const float* conv_b_t2h   = (const float*)d_in[11];
    const float* x_proj_w_t2h = (const float*)d_in[12];
    const float* dt_proj_w_t2h= (const float*)d_in[13];
    const float* dt_proj_b_t2h= (const float*)d_in[14];
    const float* A_log_t2h    = (const float*)d_in[15];
    const float* D_t2h        = (const float*)d_in[16];
    const float* lidar_w      = (const float*)d_in[17];
    const float* lidar_b      = (const float*)d_in[18];
    const float* out_proj_w   = (const float*)d_in[19];
    float* out = (float*)d_out;

    const size_t MN = (size_t)BATCH * L_SEQ * DINNER;   // 4M floats
    const size_t PS = (size_t)BATCH * L_SEQ * NP;       // 256K floats
    float* ws = (float*)d_ws;
    float* cam_x   = ws + 0 * MN;
    float* cam_z   = ws + 1 * MN;
    float* cam_xg  = ws + 2 * MN;
    float* lidar_x = ws + 3 * MN;
    float* xact0   = ws + 4 * MN;
    float* xact1   = ws + 5 * MN;
    float* sp0     = ws + 6 * MN;   // softplus(delta+bias), precomputed in GEMM epi
    float* sp1     = ws + 7 * MN;
    float* ssmp0   = ws + 8 * MN;
    float* ssmp1   = ssmp0 + PS;
    float* hC      = ssmp1 + PS;    // 4M floats
    float* PA      = cam_x;         // dead after x_proj/gate GEMMs; exactly MN floats
    float* y0 = lidar_x;            // dead after gate GEMM
    float* y1 = cam_xg;             // dead after conv kernel

    const int M = BATCH * L_SEQ;    // 4096
    dim3 blk(256);

    // 1. cam_xz = camera @ in_proj^T, split into cam_x / cam_z
    gemm64<<<dim3(2048 / 64, M / 64), blk, 0, stream>>>(
        camera_feats, nullptr, DMODEL, in_proj_w, DMODEL, DMODEL,
        cam_x, cam_z, 0, nullptr, nullptr, 1, DINNER);
    // 2. lidar_x = lidar @ in_proj[:DINNER]^T
    gemm64<<<dim3(DINNER / 64, M / 64), blk, 0, stream>>>(
        lidar_feats, nullptr, DMODEL, in_proj_w, DMODEL, DMODEL,
        lidar_x, nullptr, DINNER, nullptr, nullptr, 0, 0);
    // 3. cam_xg = sigmoid(lidar_x @ lidar_w^T + lidar_b) * cam_x
    gemm64<<<dim3(DINNER / 64, M / 64), blk, 0, stream>>>(
        lidar_x, nullptr, DINNER, lidar_w, DINNER, DINNER,
        cam_xg, nullptr, DINNER, lidar_b, cam_x, 2, 0);
    // 4/5. ssm_p (dt_r | B | C) per direction
    gemm64<<<dim3(1, M / 64), blk, 0, stream>>>(
        cam_x, nullptr, DINNER, x_proj_w_h2t, DINNER, DINNER,
        ssmp0, nullptr, NP, nullptr, nullptr, 0, 0);
    gemm64<<<dim3(1, M / 64), blk, 0, stream>>>(
        cam_x, nullptr, DINNER, x_proj_w_t2h, DINNER, DINNER,
        ssmp1, nullptr, NP, nullptr, nullptr, 0, 0);
    // 6/7. sp = softplus(dt_r @ dt_proj^T + dt_bias)
    gemm64<<<dim3(DINNER / 64, M / 64), blk, 0, stream>>>(
        ssmp0, nullptr, NP, dt_proj_w_h2t, DTRANK, DTRANK,
        sp0, nullptr, DINNER, dt_proj_b_h2t, nullptr, 3, 0);
    gemm64<<<dim3(DINNER / 64, M / 64), blk, 0, stream>>>(
        ssmp1, nullptr, NP, dt_proj_w_t2h, DTRANK, DTRANK,
        sp1, nullptr, DINNER, dt_proj_b_t2h, nullptr, 3, 0);
    // 8. conv + SiLU, both directions
    conv_silu_kernel<<<dim3(L_SEQ, BATCH), blk, 0, stream>>>(
        cam_xg, conv_w_h2t, conv_b_h2t, conv_w_t2h, conv_b_t2h, xact0, xact1);
    // 9. chunked scan (lane-owns-half-channel)
    const int nthreads = 2 * BATCH * CH * DINNER * 2;      // 262144
    scan_phase1<<<dim3(nthreads / 256), blk, 0, stream>>>(
        sp0, sp1, xact0, xact1, ssmp0, ssmp1, A_log_h2t, A_log_t2h, PA, hC);
    scan_phase2<<<dim3(2 * BATCH * DINNER * DSTATE / 256), blk, 0, stream>>>(PA, hC);
    scan_phase3<<<dim3(nthreads / 256), blk, 0, stream>>>(
        sp0, sp1, xact0, xact1, ssmp0, ssmp1, cam_z,
        A_log_h2t, A_log_t2h, D_h2t, D_t2h, PA, y0, y1);
    // 10. out = (y0 + y1) @ out_proj^T
    gemm64<<<dim3(DMODEL / 64, M / 64), blk, 0, stream>>>(
        y0, y1, DINNER, out_proj_w, DINNER, DINNER,
        out, nullptr, DMODEL, nullptr, nullptr, 0, 0);
}

// Round 4
// 447.715 us; speedup vs baseline: 4.3338x; 1.7974x over previous
//
#include <hip/hip_runtime.h>
#include <hip/hip_bf16.h>

#define L_SEQ 2048
#define BATCH 2
#define DMODEL 512
#define DINNER 1024
#define DSTATE 16
#define DTRANK 32
#define NP 64   // DT_RANK + 2*D_STATE
#define CH 32   // scan chunks
#define LC 64   // L_SEQ / CH

typedef __attribute__((ext_vector_type(8))) short bf16x8;
typedef __attribute__((ext_vector_type(4))) float f32x4;

__device__ __forceinline__ float sigmoidf_(float x) { return 1.f / (1.f + __expf(-x)); }

// pack two fp32 into two truncated bf16 (low half = x, high half = y)
__device__ __forceinline__ unsigned pk2_(float x, float y) {
    return (__float_as_uint(x) >> 16) | (__float_as_uint(y) & 0xFFFF0000u);
}
__device__ __forceinline__ float hi_of_(float x) {
    return __uint_as_float(__float_as_uint(x) & 0xFFFF0000u);
}

// ---------------- split-bf16 MFMA GEMM ----------------
// C[M,N] = (A (+A2))[M,K] @ W[N,K]^T  via a=ah+al, b=bh+bl, a*b ~= ah*bh+ah*bl+al*bh
// 128x128 tile, BK=64, 256 thr = 4 waves (2x2), wave = 64x64 out = 4x4 frags 16x16x32.
// W2 (dual mode, bcol must be 0): B rows >=64 come from W2[row-64].
// epi 0: C0[r*ldc+c] = v
// epi 1: c<nsplit -> C0[r*nsplit+c] else C1[r*nsplit+c-nsplit]
// epi 2: C0 = sigmoid(v+bias[c]) * mulsrc[r*ldc+c]
__global__ __launch_bounds__(256) void mfma_gemm(
    const float* __restrict__ A, const float* __restrict__ A2, int lda,
    const float* __restrict__ W, const float* __restrict__ W2, int ldw, int K,
    float* __restrict__ C0, float* __restrict__ C1, int ldc,
    const float* __restrict__ bias, const float* __restrict__ mulsrc,
    int epi, int nsplit)
{
    __shared__ __align__(16) char lds_buf[65536];
    char* Ah = lds_buf;
    char* Al = lds_buf + 16384;
    char* Bh = lds_buf + 32768;
    char* Bl = lds_buf + 49152;

    const int tid = threadIdx.x;
    const int brow = blockIdx.y * 128;
    const int bcol = blockIdx.x * 128;

    // staging mapping: thread -> (row 0..127, k-half 0..1) covering 32 fp32
    const int srow = tid >> 1;
    const int shalf = tid & 1;
    const int sw_s = (srow & 7) << 4;

    // fragment mapping
    const int lane = tid & 63;
    const int wv = tid >> 6;
    const int wm = (wv >> 1) * 64;
    const int wn = (wv & 1) * 64;
    const int lrow = lane & 15;
    const int lk16 = (lane >> 4) * 16;   // byte offset of 8-elem k-group
    const int sw_r = (lrow & 7) << 4;

    int aoff[4], boff[4];
    #pragma unroll
    for (int m = 0; m < 4; ++m) aoff[m] = (wm + m * 16 + lrow) * 128 + lk16;
    #pragma unroll
    for (int n = 0; n < 4; ++n) boff[n] = (wn + n * 16 + lrow) * 128 + lk16;

    const float* Arow = A + (size_t)(brow + srow) * lda + shalf * 32;
    const float* A2row = A2 ? A2 + (size_t)(brow + srow) * lda + shalf * 32 : nullptr;
    const float* Wrow;
    if (W2 && srow >= 64) Wrow = W2 + (size_t)(srow - 64) * ldw + shalf * 32;
    else                  Wrow = W + (size_t)(bcol + srow) * ldw + shalf * 32;

    f32x4 acc[4][4];
    #pragma unroll
    for (int m = 0; m < 4; ++m)
        #pragma unroll
        for (int n = 0; n < 4; ++n)
            acc[m][n] = (f32x4){0.f, 0.f, 0.f, 0.f};

    const int wbase = srow * 128 + shalf * 64;

    for (int k0 = 0; k0 < K; k0 += 64) {
        float4 va[8], vb[8];
        #pragma unroll
        for (int j = 0; j < 8; ++j) va[j] = *(const float4*)(Arow + j * 4);
        if (A2row) {
            #pragma unroll
            for (int j = 0; j < 8; ++j) {
                float4 t = *(const float4*)(A2row + j * 4);
                va[j].x += t.x; va[j].y += t.y; va[j].z += t.z; va[j].w += t.w;
            }
        }
        #pragma unroll
        for (int j = 0; j < 8; ++j) vb[j] = *(const float4*)(Wrow + j * 4);
        Arow += 64; Wrow += 64;
        if (A2row) A2row += 64;

        __syncthreads();   // previous iteration's LDS reads complete

        #pragma unroll
        for (int t = 0; t < 4; ++t) {
            float4 v0 = va[2 * t], v1 = va[2 * t + 1];
            uint4 H, L;
            H.x = pk2_(v0.x, v0.y); H.y = pk2_(v0.z, v0.w);
            H.z = pk2_(v1.x, v1.y); H.w = pk2_(v1.z, v1.w);
            float l0x = v0.x - hi_of_(v0.x), l0y = v0.y - hi_of_(v0.y);
            float l0z = v0.z - hi_of_(v0.z), l0w = v0.w - hi_of_(v0.w);
            float l1x = v1.x - hi_of_(v1.x), l1y = v1.y - hi_of_(v1.y);
            float l1z = v1.z - hi_of_(v1.z), l1w = v1.w - hi_of_(v1.w);
            L.x = pk2_(l0x, l0y); L.y = pk2_(l0z, l0w);
            L.z = pk2_(l1x, l1y); L.w = pk2_(l1z, l1w);
            int ad = (wbase + t * 16) ^ sw_s;
            *(uint4*)(Ah + ad) = H;
            *(uint4*)(Al + ad) = L;
        }
        #pragma unroll
        for (int t = 0; t < 4; ++t) {
            float4 v0 = vb[2 * t], v1 = vb[2 * t + 1];
            uint4 H, L;
            H.x = pk2_(v0.x, v0.y); H.y = pk2_(v0.z, v0.w);
            H.z = pk2_(v1.x, v1.y); H.w = pk2_(v1.z, v1.w);
            float l0x = v0.x - hi_of_(v0.x), l0y = v0.y - hi_of_(v0.y);
            float l0z = v0.z - hi_of_(v0.z), l0w = v0.w - hi_of_(v0.w);
            float l1x = v1.x - hi_of_(v1.x), l1y = v1.y - hi_of_(v1.y);
            float l1z = v1.z - hi_of_(v1.z), l1w = v1.w - hi_of_(v1.w);
            L.x = pk2_(l0x, l0y); L.y = pk2_(l0z, l0w);
            L.z = pk2_(l1x, l1y); L.w = pk2_(l1z, l1w);
            int ad = (wbase + t * 16) ^ sw_s;
            *(uint4*)(Bh + ad) = H;
            *(uint4*)(Bl + ad) = L;
        }
        __syncthreads();

        #pragma unroll
        for (int kc = 0; kc < 2; ++kc) {
            bf16x8 fah[4], fal[4], fbh[4], fbl[4];
            #pragma unroll
            for (int m = 0; m < 4; ++m) {
                int off = (aoff[m] + kc * 64) ^ sw_r;
                fah[m] = *(const bf16x8*)(Ah + off);
                fal[m] = *(const bf16x8*)(Al + off);
            }
            #pragma unroll
            for (int n = 0; n < 4; ++n) {
                int off = (boff[n] + kc * 64) ^ sw_r;
                fbh[n] = *(const bf16x8*)(Bh + off);
                fbl[n] = *(const bf16x8*)(Bl + off);
            }
            #pragma unroll
            for (int m = 0; m < 4; ++m)
                #pragma unroll
                for (int n = 0; n < 4; ++n) {
                    acc[m][n] = __builtin_amdgcn_mfma_f32_16x16x32_bf16(fah[m], fbh[n], acc[m][n], 0, 0, 0);
                    acc[m][n] = __builtin_amdgcn_mfma_f32_16x16x32_bf16(fah[m], fbl[n], acc[m][n], 0, 0, 0);
                    acc[m][n] = __builtin_amdgcn_mfma_f32_16x16x32_bf16(fal[m], fbh[n], acc[m][n], 0, 0, 0);
                }
        }
    }

    // epilogue: D frag (m,n) reg r -> row = wm+m*16+(lane>>4)*4+r, col = wn+n*16+(lane&15)
    const int erow0 = brow + wm + (lane >> 4) * 4;
    const int ecol0 = bcol + wn + (lane & 15);
    #pragma unroll
    for (int m = 0; m < 4; ++m)
        #pragma unroll
        for (int n = 0; n < 4; ++n)
            #pragma unroll
            for (int r = 0; r < 4; ++r) {
                int row = erow0 + m * 16 + r;
                int col = ecol0 + n * 16;
                float v = acc[m][n][r];
                if (epi == 0) {
                    C0[(size_t)row * ldc + col] = v;
                } else if (epi == 1) {
                    if (col < nsplit) C0[(size_t)row * nsplit + col] = v;
                    else              C1[(size_t)row * nsplit + (col - nsplit)] = v;
                } else {
                    float g = sigmoidf_(v + bias[col]);
                    C0[(size_t)row * ldc + col] = g * mulsrc[(size_t)row * ldc + col];
                }
            }
}

// ---------------- fp32 fallback GEMM (dt_proj only: K=32) ----------------
// epi 3: C0 = softplus(v + bias[c])
__global__ __launch_bounds__(256) void gemm64(
    const float* __restrict__ A, const float* __restrict__ A2, int lda,
    const float* __restrict__ W, int ldw, int K,
    float* __restrict__ C0, float* __restrict__ C1, int ldc,
    const float* __restrict__ bias, const float* __restrict__ mulsrc,
    int epi, int nsplit)
{
    __shared__ float As[16][65];
    __shared__ float Ws[16][65];
    const int tid = threadIdx.x;
    const int tx = tid & 15, ty = tid >> 4;
    const int row0 = blockIdx.y * 64;
    const int col0 = blockIdx.x * 64;
    const int lr = tid >> 2;
    const int lk = (tid & 3) * 4;
    float acc[4][4] = {};

    for (int k0 = 0; k0 < K; k0 += 16) {
        float4 av = *(const float4*)(A + (size_t)(row0 + lr) * lda + k0 + lk);
        if (A2) {
            float4 bv = *(const float4*)(A2 + (size_t)(row0 + lr) * lda + k0 + lk);
            av.x += bv.x; av.y += bv.y; av.z += bv.z; av.w += bv.w;
        }
        As[lk + 0][lr] = av.x; As[lk + 1][lr] = av.y;
        As[lk + 2][lr] = av.z; As[lk + 3][lr] = av.w;
        float4 wv = *(const float4*)(W + (size_t)(col0 + lr) * ldw + k0 + lk);
        Ws[lk + 0][lr] = wv.x; Ws[lk + 1][lr] = wv.y;
        Ws[lk + 2][lr] = wv.z; Ws[lk + 3][lr] = wv.w;
        __syncthreads();
        #pragma unroll
        for (int kk = 0; kk < 16; ++kk) {
            float a[4], b[4];
            #pragma unroll
            for (int i = 0; i < 4; ++i) a[i] = As[kk][ty * 4 + i];
            #pragma unroll
            for (int j = 0; j < 4; ++j) b[j] = Ws[kk][tx * 4 + j];
            #pragma unroll
            for (int i = 0; i < 4; ++i)
                #pragma unroll
                for (int j = 0; j < 4; ++j)
                    acc[i][j] = fmaf(a[i], b[j], acc[i][j]);
        }
        __syncthreads();
    }

    #pragma unroll
    for (int i = 0; i < 4; ++i) {
        int r = row0 + ty * 4 + i;
        #pragma unroll
        for (int j = 0; j < 4; ++j) {
            int c = col0 + tx * 4 + j;
            float v = acc[i][j];
            if (epi == 0) {
                C0[(size_t)r * ldc + c] = v;
            } else if (epi == 1) {
                if (c < nsplit) C0[(size_t)r * nsplit + c] = v;
                else            C1[(size_t)r * nsplit + (c - nsplit)] = v;
            } else if (epi == 2) {
                float g = sigmoidf_(v + bias[c]);
                C0[(size_t)r * ldc + c] = g * mulsrc[(size_t)r * ldc + c];
            } else {
                float x = v + bias[c];
                float sp = (x > 20.f) ? x : __logf(1.f + __expf(x));
                C0[(size_t)r * ldc + c] = sp;
            }
        }
    }
}

// Depthwise causal conv (h2t) + anti-causal reversed conv (t2h) + SiLU, both dirs.
__global__ __launch_bounds__(256) void conv_silu_kernel(
    const float* __restrict__ xg,
    const float* __restrict__ w0, const float* __restrict__ b0,
    const float* __restrict__ w1, const float* __restrict__ b1,
    float* __restrict__ out0, float* __restrict__ out1)
{
    const int l = blockIdx.x;
    const int b = blockIdx.y;
    const int d0 = threadIdx.x * 4;
    const size_t bbase = (size_t)b * L_SEQ * DINNER + d0;

    float tap[7][4];
    #pragma unroll
    for (int p = 0; p < 7; ++p) {
        int ll = l + p - 3;
        if (ll >= 0 && ll < L_SEQ) {
            float4 v = *(const float4*)(xg + bbase + (size_t)ll * DINNER);
            tap[p][0] = v.x; tap[p][1] = v.y; tap[p][2] = v.z; tap[p][3] = v.w;
        } else {
            tap[p][0] = tap[p][1] = tap[p][2] = tap[p][3] = 0.f;
        }
    }
    float4 bb0 = *(const float4*)(b0 + d0);
    float4 bb1 = *(const float4*)(b1 + d0);
    float r0[4], r1[4];
    #pragma unroll
    for (int i = 0; i < 4; ++i) {
        float4 ww0 = *(const float4*)(w0 + (d0 + i) * 4);
        float4 ww1 = *(const float4*)(w1 + (d0 + i) * 4);
        float a0 = ((const float*)&bb0)[i];
        a0 += ww0.x * tap[0][i] + ww0.y * tap[1][i] + ww0.z * tap[2][i] + ww0.w * tap[3][i];
        float a1 = ((const float*)&bb1)[i];
        a1 += ww1.w * tap[3][i] + ww1.z * tap[4][i] + ww1.y * tap[5][i] + ww1.x * tap[6][i];
        r0[i] = a0 * sigmoidf_(a0);
        r1[i] = a1 * sigmoidf_(a1);
    }
    *(float4*)(out0 + bbase + (size_t)l * DINNER) = make_float4(r0[0], r0[1], r0[2], r0[3]);
    *(float4*)(out1 + bbase + (size_t)l * DINNER) = make_float4(r1[0], r1[1], r1[2], r1[3]);
}

// ---- Chunked selective scan, lane-owns-half-channel ----
__global__ __launch_bounds__(256) void scan_phase1(
    const float* __restrict__ sp0, const float* __restrict__ sp1,
    const float* __restrict__ xa0, const float* __restrict__ xa1,
    const float* __restrict__ pm0, const float* __restrict__ pm1,
    const float* __restrict__ Alog0, const float* __restrict__ Alog1,
    float* __restrict__ PA, float* __restrict__ hC)
{
    __shared__ float sBC[LC][32];
    const int tid = threadIdx.x;
    const int flat = blockIdx.x * 256 + tid;
    const int half = flat & 1;
    const int d = (flat >> 1) & (DINNER - 1);
    const int rest = flat >> 11;
    const int chunk = rest & (CH - 1);
    const int bb = rest >> 5;
    const int b = bb & 1;
    const int dir = bb >> 1;

    const float* __restrict__ sp = dir ? sp1 : sp0;
    const float* __restrict__ u  = dir ? xa1 : xa0;
    const float* __restrict__ pm = dir ? pm1 : pm0;
    const float* __restrict__ Alog = dir ? Alog1 : Alog0;

    const int step = dir ? -1 : 1;
    const int l0 = dir ? (L_SEQ - 1 - chunk * LC) : (chunk * LC);

    {
        const int base = (b * L_SEQ + l0) * NP + DTRANK;
        #pragma unroll
        for (int j = 0; j < (LC * 32) / 256; ++j) {
            int e = tid + j * 256;
            int s = e >> 5, k = e & 31;
            sBC[s][k] = pm[base + step * s * NP + k];
        }
    }
    __syncthreads();

    float Adn[8];
    #pragma unroll
    for (int n = 0; n < 8; ++n)
        Adn[n] = -__expf(Alog[d * DSTATE + half * 8 + n]);

    int idx = (b * L_SEQ + l0) * DINNER + d;
    const int idxstep = step * DINNER;

    float h[8] = {0.f,0.f,0.f,0.f,0.f,0.f,0.f,0.f};
    float pa[8] = {1.f,1.f,1.f,1.f,1.f,1.f,1.f,1.f};

    float spv = sp[idx], uv = u[idx];
    for (int s = 0; s < LC; ++s) {
        const int idx2 = idx + ((s + 1 < LC) ? idxstep : 0);
        float spn = sp[idx2], un = u[idx2];
        float4 Bv0 = *(const float4*)&sBC[s][half * 8];
        float4 Bv1 = *(const float4*)&sBC[s][half * 8 + 4];
        float sbu = spv * uv;
        const float* Bp0 = (const float*)&Bv0;
        const float* Bp1 = (const float*)&Bv1;
        #pragma unroll
        for (int n = 0; n < 8; ++n) {
            float dA = __expf(spv * Adn[n]);
            pa[n] *= dA;
            float Bn = (n < 4) ? Bp0[n] : Bp1[n - 4];
            h[n] = fmaf(dA, h[n], Bn * sbu);
        }
        idx += idxstep; spv = spn; uv = un;
    }

    const int o = rest * (DINNER * DSTATE) + d * DSTATE + half * 8;
    *(float4*)&PA[o]     = make_float4(pa[0], pa[1], pa[2], pa[3]);
    *(float4*)&PA[o + 4] = make_float4(pa[4], pa[5], pa[6], pa[7]);
    *(float4*)&hC[o]     = make_float4(h[0], h[1], h[2], h[3]);
    *(float4*)&hC[o + 4] = make_float4(h[4], h[5], h[6], h[7]);
}

__global__ __launch_bounds__(256) void scan_phase2(
    float* __restrict__ PA, const float* __restrict__ hC)
{
    const int flat = blockIdx.x * 256 + threadIdx.x;
    const int dn = flat & (DINNER * DSTATE - 1);
    const int bb = flat >> 14;
    const int base = bb * CH * (DINNER * DSTATE) + dn;
    float hrun = 0.f;
    #pragma unroll 4
    for (int c = 0; c < CH; ++c) {
        const int o = base + c * (DINNER * DSTATE);
        float pa = PA[o];
        float hc = hC[o];
        PA[o] = hrun;
        hrun = fmaf(pa, hrun, hc);
    }
}

__global__ __launch_bounds__(256) void scan_phase3(
    const float* __restrict__ sp0, const float* __restrict__ sp1,
    const float* __restrict__ xa0, const float* __restrict__ xa1,
    const float* __restrict__ pm0, const float* __restrict__ pm1,
    const float* __restrict__ camz,
    const float* __restrict__ Alog0, const float* __restrict__ Alog1,
    const float* __restrict__ Dv0, const float* __restrict__ Dv1,
    const float* __restrict__ hin,
    float* __restrict__ y0, float* __restrict__ y1)
{
    __shared__ float sBC[LC][32];
    const int tid = threadIdx.x;
    const int flat = blockIdx.x * 256 + tid;
    const int half = flat & 1;
    const int d = (flat >> 1) & (DINNER - 1);
    const int rest = flat >> 11;
    const int chunk = rest & (CH - 1);
    const int bb = rest >> 5;
    const int b = bb & 1;
    const int dir = bb >> 1;

    const float* __restrict__ sp = dir ? sp1 : sp0;
    const float* __restrict__ u  = dir ? xa1 : xa0;
    const float* __restrict__ pm = dir ? pm1 : pm0;
    const float* __restrict__ Alog = dir ? Alog1 : Alog0;
    const float* __restrict__ Dv = dir ? Dv1 : Dv0;
    float* __restrict__ yo = dir ? y1 : y0;

    const int step = dir ? -1 : 1;
    const int l0 = dir ? (L_SEQ - 1 - chunk * LC) : (chunk * LC);

    {
        const int base = (b * L_SEQ + l0) * NP + DTRANK;
        #pragma unroll
        for (int j = 0; j < (LC * 32) / 256; ++j) {
            int e = tid + j * 256;
            int s = e >> 5, k = e & 31;
            sBC[s][k] = pm[base + step * s * NP + k];
        }
    }
    __syncthreads();

    float Adn[8];
    #pragma unroll
    for (int n = 0; n < 8; ++n)
        Adn[n] = -__expf(Alog[d * DSTATE + half * 8 + n]);
    const float Dd = Dv[d];

    int idx = (b * L_SEQ + l0) * DINNER + d;
    const int idxstep = step * DINNER;

    const int o = rest * (DINNER * DSTATE) + d * DSTATE + half * 8;
    float4 h0 = *(const float4*)&hin[o];
    float4 h1 = *(const float4*)&hin[o + 4];
    float h[8] = {h0.x, h0.y, h0.z, h0.w, h1.x, h1.y, h1.z, h1.w};

    float spv = sp[idx], uv = u[idx], zv = camz[idx];
    for (int s = 0; s < LC; ++s) {
        const int idx2 = idx + ((s + 1 < LC) ? idxstep : 0);
        float spn = sp[idx2], un = u[idx2], zn = camz[idx2];
        float4 Bv0 = *(const float4*)&sBC[s][half * 8];
        float4 Bv1 = *(const float4*)&sBC[s][half * 8 + 4];
        float4 Cv0 = *(const float4*)&sBC[s][16 + half * 8];
        float4 Cv1 = *(const float4*)&sBC[s][16 + half * 8 + 4];
        const float* Bp0 = (const float*)&Bv0;
        const float* Bp1 = (const float*)&Bv1;
        const float* Cp0 = (const float*)&Cv0;
        const float* Cp1 = (const float*)&Cv1;
        float sbu = spv * uv;
        float acc = 0.f;
        #pragma unroll
        for (int n = 0; n < 8; ++n) {
            float dA = __expf(spv * Adn[n]);
            float Bn = (n < 4) ? Bp0[n] : Bp1[n - 4];
            float Cn = (n < 4) ? Cp0[n] : Cp1[n - 4];
            h[n] = fmaf(dA, h[n], Bn * sbu);
            acc = fmaf(h[n], Cn, acc);
        }
        acc += __shfl_xor(acc, 1);
        if (half == 0) {
            float sz = zv * sigmoidf_(zv);
            yo[idx] = (acc + uv * Dd) * sz;
        }
        idx += idxstep; spv = spn; uv = un; zv = zn;
    }
}

extern "C" void kernel_launch(void* const* d_in, const int* in_sizes, int n_in,
                              void* d_out, int out_size, void* d_ws, size_t ws_size,
                              hipStream_t stream)
{
    const float* lidar_feats  = (const float*)d_in[0];
    const float* camera_feats = (const float*)d_in[1];
    const float* in_proj_w    = (const float*)d_in[2];
    const float* conv_w_h2t   = (const float*)d_in[3];
    const float* conv_b_h2t   = (const float*)d_in[4];
    const float* x_proj_w_h2t = (const float*)d_in[5];
    const float* dt_proj_w_h2t= (const float*)d_in[6];
    const float* dt_proj_b_h2t= (const float*)d_in[7];
    const float* A_log_h2t    = (const float*)d_in[8];
    const float* D_h2t        = (const float*)d_in[9];
    const float* conv_w_t2h   = (const float*)d_in[10];
    const float* conv_b_t2h   = (const float*)d_in[11];
    const float* x_proj_w_t2h = (const float*)d_in[12];
    const float* dt_proj_w_t2h= (const float*)d_in[13];
    const float* dt_proj_b_t2h= (const float*)d_in[14];
    const float* A_log_t2h    = (const float*)d_in[15];
    const float* D_t2h        = (const float*)d_in[16];
    const float* lidar_w      = (const float*)d_in[17];
    const float* lidar_b      = (const float*)d_in[18];
    const float* out_proj_w   = (const float*)d_in[19];
    float* out = (float*)d_out;

    const size_t MN = (size_t)BATCH * L_SEQ * DINNER;   // 4M floats
    const size_t PS = (size_t)BATCH * L_SEQ * NP;       // 256K floats
    float* ws = (float*)d_ws;
    float* cam_x   = ws + 0 * MN;
    float* cam_z   = ws + 1 * MN;
    float* cam_xg  = ws + 2 * MN;
    float* lidar_x = ws + 3 * MN;
    float* xact0   = ws + 4 * MN;
    float* xact1   = ws + 5 * MN;
    float* sp0     = ws + 6 * MN;
    float* sp1     = ws + 7 * MN;
    float* ssmp0   = ws + 8 * MN;
    float* ssmp1   = ssmp0 + PS;
    float* hC      = ssmp1 + PS;
    float* PA      = cam_x;         // dead after x_proj/gate GEMMs
    float* y0 = lidar_x;            // dead after gate GEMM
    float* y1 = cam_xg;             // dead after conv kernel

    const int M = BATCH * L_SEQ;    // 4096
    dim3 blk(256);

    // 1. cam_xz = camera @ in_proj^T, split into cam_x / cam_z   (MFMA split-bf16)
    mfma_gemm<<<dim3(2048 / 128, M / 128), blk, 0, stream>>>(
        camera_feats, nullptr, DMODEL, in_proj_w, nullptr, DMODEL, DMODEL,
        cam_x, cam_z, 0, nullptr, nullptr, 1, DINNER);
    // 2. lidar_x = lidar @ in_proj[:DINNER]^T
    mfma_gemm<<<dim3(DINNER / 128, M / 128), blk, 0, stream>>>(
        lidar_feats, nullptr, DMODEL, in_proj_w, nullptr, DMODEL, DMODEL,
        lidar_x, nullptr, DINNER, nullptr, nullptr, 0, 0);
    // 3. cam_xg = sigmoid(lidar_x @ lidar_w^T + lidar_b) * cam_x
    mfma_gemm<<<dim3(DINNER / 128, M / 128), blk, 0, stream>>>(
        lidar_x, nullptr, DINNER, lidar_w, nullptr, DINNER, DINNER,
        cam_xg, nullptr, DINNER, lidar_b, cam_x, 2, 0);
    // 4. ssm_p both directions in one dual-weight call (N=128: 64 h2t | 64 t2h)
    mfma_gemm<<<dim3(1, M / 128), blk, 0, stream>>>(
        cam_x, nullptr, DINNER, x_proj_w_h2t, x_proj_w_t2h, DINNER, DINNER,
        ssmp0, ssmp1, 0, nullptr, nullptr, 1, NP);
    // 5/6. sp = softplus(dt_r @ dt_proj^T + dt_bias)  (K=32: fp32 gemm64)
    gemm64<<<dim3(DINNER / 64, M / 64), blk, 0, stream>>>(
        ssmp0, nullptr, NP, dt_proj_w_h2t, DTRANK, DTRANK,
        sp0, nullptr, DINNER, dt_proj_b_h2t, nullptr, 3, 0);
    gemm64<<<dim3(DINNER / 64, M / 64), blk, 0, stream>>>(
        ssmp1, nullptr, NP, dt_proj_w_t2h, DTRANK, DTRANK,
        sp1, nullptr, DINNER, dt_proj_b_t2h, nullptr, 3, 0);
    // 7. conv + SiLU, both directions
    conv_silu_kernel<<<dim3(L_SEQ, BATCH), blk, 0, stream>>>(
        cam_xg, conv_w_h2t, conv_b_h2t, conv_w_t2h, conv_b_t2h, xact0, xact1);
    // 8. chunked scan
    const int nthreads = 2 * BATCH * CH * DINNER * 2;      // 262144
    scan_phase1<<<dim3(nthreads / 256), blk, 0, stream>>>(
        sp0, sp1, xact0, xact1, ssmp0, ssmp1, A_log_h2t, A_log_t2h, PA, hC);
    scan_phase2<<<dim3(2 * BATCH * DINNER * DSTATE / 256), blk, 0, stream>>>(PA, hC);
    scan_phase3<<<dim3(nthreads / 256), blk, 0, stream>>>(
        sp0, sp1, xact0, xact1, ssmp0, ssmp1, cam_z,
        A_log_h2t, A_log_t2h, D_h2t, D_t2h, PA, y0, y1);
    // 9. out = (y0 + y1) @ out_proj^T
    mfma_gemm<<<dim3(DMODEL / 128, M / 128), blk, 0, stream>>>(
        y0, y1, DINNER, out_proj_w, nullptr, DINNER, DINNER,
        out, nullptr, DMODEL, nullptr, nullptr, 0, 0);
}